// Round 7
// baseline (1778.548 us; speedup 1.0000x reference)
//
#include <hip/hip_runtime.h>

// =====================================================================
// DecoderLayer: selfMHA -> LN -> crossMHA -> LN -> 32xLSTM(pipelined)
//               -> pointwise conv -> LN
// Round 7: R6 MFMA-LSTM with the register spill fixed:
//          __launch_bounds__(64,1) (512-VGPR budget, no scratch) and the
//          per-chunk x prefetch staged through LDS instead of 32 VGPRs.
//          GEMM/attention unchanged.
// =====================================================================

#define EPS_LN 1e-5f

typedef _Float16 h8v __attribute__((ext_vector_type(8)));
typedef float    f4v __attribute__((ext_vector_type(4)));

// ---------------- fused weight prep: 8 transposes + 1 straight cvt -------
struct WPtrs { const float* p[9]; };

__global__ __launch_bounds__(256)
void prep_weights(WPtrs w, _Float16* __restrict__ dst) {
  __shared__ float tile[32][33];
  const int z = blockIdx.z;
  const int tx = threadIdx.x & 31, ty = threadIdx.x >> 5;
  const int bx = blockIdx.x, by = blockIdx.y;
  const float* in = w.p[z];
  _Float16* outp = dst + (size_t)z * 262144;
  if (z < 8) {
#pragma unroll
    for (int i = 0; i < 4; i++)
      tile[ty + i * 8][tx] = in[(size_t)(by * 32 + ty + i * 8) * 512 + bx * 32 + tx];
    __syncthreads();
#pragma unroll
    for (int i = 0; i < 4; i++)
      outp[(size_t)(bx * 32 + ty + i * 8) * 512 + by * 32 + tx] = (_Float16)tile[tx][ty + i * 8];
  } else {
#pragma unroll
    for (int i = 0; i < 4; i++) {
      size_t off = (size_t)(by * 32 + ty + i * 8) * 512 + bx * 32 + tx;
      outp[off] = (_Float16)in[off];
    }
  }
}

// ---------------- f16 MFMA GEMM, fp32 A staged+converted in LDS ----------
__global__ __launch_bounds__(256)
void gemm3(const float* __restrict__ A,
           const _Float16* __restrict__ BT0, const _Float16* __restrict__ BT1,
           const _Float16* __restrict__ BT2,
           const float* __restrict__ bias0, const float* __restrict__ bias1,
           const float* __restrict__ bias2,
           float* __restrict__ C0, float* __restrict__ C1, float* __restrict__ C2,
           int M) {
  __shared__ _Float16 Asld[64 * 40];
  __shared__ _Float16 Bsld[64 * 40];
  const int t = threadIdx.x;
  const int which = blockIdx.x >> 3;
  const int n0 = (blockIdx.x & 7) * 64;
  const int m0 = blockIdx.y * 64;
  const _Float16* BT = (which == 0) ? BT0 : (which == 1) ? BT1 : BT2;
  const float* bias  = (which == 0) ? bias0 : (which == 1) ? bias1 : bias2;
  float* C           = (which == 0) ? C0 : (which == 1) ? C1 : C2;

  const int r = t >> 2, q = t & 3;
  const int w = t >> 6;
  const int lane = t & 63;
  const int lm = lane & 15, q8 = lane >> 4;

  f4v acc[4] = {};
  for (int k0 = 0; k0 < 512; k0 += 32) {
    __syncthreads();
    float4 f0 = *(const float4*)&A[(size_t)(m0 + r) * 512 + k0 + q * 8];
    float4 f1 = *(const float4*)&A[(size_t)(m0 + r) * 512 + k0 + q * 8 + 4];
    h8v hvv = {(_Float16)f0.x, (_Float16)f0.y, (_Float16)f0.z, (_Float16)f0.w,
               (_Float16)f1.x, (_Float16)f1.y, (_Float16)f1.z, (_Float16)f1.w};
    *(h8v*)&Asld[r * 40 + q * 8] = hvv;
    *(uint4*)&Bsld[r * 40 + q * 8] = *(const uint4*)&BT[(size_t)(n0 + r) * 512 + k0 + q * 8];
    __syncthreads();
    h8v a = *(const h8v*)&Asld[(w * 16 + lm) * 40 + q8 * 8];
#pragma unroll
    for (int nt = 0; nt < 4; nt++) {
      h8v b = *(const h8v*)&Bsld[(nt * 16 + lm) * 40 + q8 * 8];
      acc[nt] = __builtin_amdgcn_mfma_f32_16x16x32_f16(a, b, acc[nt], 0, 0, 0);
    }
  }
#pragma unroll
  for (int nt = 0; nt < 4; nt++) {
    int gn = n0 + nt * 16 + lm;
    float bv = bias[gn];
#pragma unroll
    for (int rg = 0; rg < 4; rg++) {
      int gm = m0 + w * 16 + q8 * 4 + rg;
      C[(size_t)gm * 512 + gn] = acc[nt][rg] + bv;
    }
  }
}

// ---------------- attention: scores then softmax+PV, per (b,h) -----------
template <int S>
__global__ __launch_bounds__(256)
void attn_scores(const float* __restrict__ Q, const float* __restrict__ K,
                 float* __restrict__ P) {
  __shared__ float Qs[25][64];
  __shared__ float Ks[S][65];
  const int h = blockIdx.x, b = blockIdx.y, t = threadIdx.x;
  for (int idx = t; idx < 25 * 64; idx += 256) {
    int l = idx >> 6, e = idx & 63;
    Qs[l][e] = Q[(b * 25 + l) * 512 + h * 64 + e];
  }
  for (int idx = t; idx < S * 64; idx += 256) {
    int s = idx >> 6, e = idx & 63;
    Ks[s][e] = K[(b * S + s) * 512 + h * 64 + e];
  }
  __syncthreads();
  float* Pb = P + (size_t)(b * 8 + h) * 25 * S;
  for (int idx = t; idx < 25 * S; idx += 256) {
    int l = idx / S, s = idx % S;
    float acc = 0.f;
#pragma unroll
    for (int e = 0; e < 64; e++) acc += Qs[l][e] * Ks[s][e];
    Pb[idx] = acc * 0.125f;
  }
}

template <int S>
__global__ __launch_bounds__(256)
void attn_out(const float* __restrict__ P, const float* __restrict__ V,
              float* __restrict__ O) {
  __shared__ float Ps[25][S];
  __shared__ float Vs[S][64];
  const int h = blockIdx.x, b = blockIdx.y, t = threadIdx.x;
  const float* Pb = P + (size_t)(b * 8 + h) * 25 * S;
  for (int idx = t; idx < 25 * S; idx += 256) Ps[idx / S][idx % S] = Pb[idx];
  for (int idx = t; idx < S * 64; idx += 256) {
    int s = idx >> 6, e = idx & 63;
    Vs[s][e] = V[(b * S + s) * 512 + h * 64 + e];
  }
  __syncthreads();
  if (t < 25) {
    float mx = -1e30f;
    for (int s = 0; s < S; s++) mx = fmaxf(mx, Ps[t][s]);
    float sum = 0.f;
    for (int s = 0; s < S; s++) { float p = __expf(Ps[t][s] - mx); Ps[t][s] = p; sum += p; }
    float r = 1.f / sum;
    for (int s = 0; s < S; s++) Ps[t][s] *= r;
  }
  __syncthreads();
  for (int idx = t; idx < 25 * 64; idx += 256) {
    int l = idx >> 6, e = idx & 63;
    float acc = 0.f;
    for (int s = 0; s < S; s++) acc += Ps[l][s] * Vs[s][e];
    O[(b * 25 + l) * 512 + h * 64 + e] = acc;
  }
}

// ---------------- fused residual-add + LayerNorm (rows of 512) -----------
__global__ __launch_bounds__(128)
void add_ln(const float* __restrict__ a, const float* __restrict__ b,
            const float* __restrict__ gw, const float* __restrict__ bw,
            float* __restrict__ out) {
  const int row = blockIdx.x, t = threadIdx.x;
  float4 va = ((const float4*)(a + (size_t)row * 512))[t];
  float4 vb = ((const float4*)(b + (size_t)row * 512))[t];
  float4 v = make_float4(va.x + vb.x, va.y + vb.y, va.z + vb.z, va.w + vb.w);
  float s = v.x + v.y + v.z + v.w;
  float q = v.x * v.x + v.y * v.y + v.z * v.z + v.w * v.w;
#pragma unroll
  for (int off = 32; off > 0; off >>= 1) {
    s += __shfl_down(s, off);
    q += __shfl_down(q, off);
  }
  __shared__ float red[4];
  if ((t & 63) == 0) { red[(t >> 6) * 2] = s; red[(t >> 6) * 2 + 1] = q; }
  __syncthreads();
  float S_ = red[0] + red[2], Q_ = red[1] + red[3];
  float mean = S_ * (1.f / 512.f);
  float var  = Q_ * (1.f / 512.f) - mean * mean;
  float inv  = rsqrtf(var + EPS_LN);
  float4 g4 = ((const float4*)gw)[t];
  float4 b4 = ((const float4*)bw)[t];
  float4 o;
  o.x = (v.x - mean) * inv * g4.x + b4.x;
  o.y = (v.y - mean) * inv * g4.y + b4.y;
  o.z = (v.z - mean) * inv * g4.z + b4.z;
  o.w = (v.w - mean) * inv * g4.w + b4.w;
  ((float4*)(out + (size_t)row * 512))[t] = o;
}

// ---------------- transposes / LSTM preps --------------------------------
__global__ void transpose_dl(const float* __restrict__ in, float* __restrict__ outp) {
  const int b = blockIdx.x, t = threadIdx.x;
  for (int idx = t; idx < 25 * 512; idx += 256) {
    int l2 = idx / 512, c = idx % 512;
    outp[((size_t)b * 25 + l2) * 512 + c] = in[((size_t)b * 512 + c) * 25 + l2];
  }
}

// Wperm[l][112][64]: row r=4u+gate, k=0..24 -> Wih, k=32..56 -> Whh, else 0.
__global__ __launch_bounds__(256)
void prep_lstm_w(const float* __restrict__ Wih, const float* __restrict__ Whh,
                 const float* __restrict__ bih, const float* __restrict__ bhh,
                 _Float16* __restrict__ Wperm, float* __restrict__ gbias) {
  const int l = blockIdx.x, t = threadIdx.x;
  for (int idx = t; idx < 112 * 64; idx += 256) {
    int r = idx >> 6, k = idx & 63;
    int u = r >> 2, gi = r & 3;
    float v = 0.f;
    if (u < 25) {
      if (k < 25) v = Wih[((size_t)l * 100 + gi * 25 + u) * 25 + k];
      else if (k >= 32 && k < 57) v = Whh[((size_t)l * 100 + gi * 25 + u) * 25 + (k - 32)];
    }
    Wperm[(size_t)l * 7168 + idx] = (_Float16)v;
  }
  for (int idx = t; idx < 112; idx += 256) {
    int u = idx >> 2, gi = idx & 3;
    float v = 0.f;
    if (u < 25) v = bih[l * 100 + gi * 25 + u] + bhh[l * 100 + gi * 25 + u];
    gbias[l * 112 + idx] = v;
  }
}

// X0[t=512][b=128][32] f16 from x2[b][25][512]
__global__ __launch_bounds__(256)
void prep_x0(const float* __restrict__ x2, _Float16* __restrict__ X0) {
  __shared__ float tile[25][516];
  const int b = blockIdx.x, t = threadIdx.x;
  for (int idx = t; idx < 25 * 512; idx += 256) {
    int u = idx >> 9, d = idx & 511;
    tile[u][d] = x2[((size_t)b * 25 + u) * 512 + d];
  }
  __syncthreads();
  for (int idx = t; idx < 512 * 32; idx += 256) {
    int d = idx >> 5, u = idx & 31;
    X0[((size_t)d * 128 + b) * 32 + u] = (u < 25) ? (_Float16)tile[u][d] : (_Float16)0.f;
  }
}

// ---------------- MFMA persistent LSTM -----------------------------------
// 256 blocks x 64 threads (1 wave = one (layer,16-batch) chain).
// Spill-proof: __launch_bounds__(64,1) -> up to 512 VGPRs; chunk x-prefetch
// staged via LDS (xlds, ring-slot layout) instead of 32 VGPRs.
__device__ __forceinline__ int ld_rlx(int* p) {
  return __hip_atomic_load(p, __ATOMIC_RELAXED, __HIP_MEMORY_SCOPE_AGENT);
}
__device__ __forceinline__ void st_rlx(int* p, int v) {
  __hip_atomic_store(p, v, __ATOMIC_RELAXED, __HIP_MEMORY_SCOPE_AGENT);
}
__device__ __forceinline__ unsigned long long ldq_rlx(const unsigned long long* p) {
  return __hip_atomic_load(p, __ATOMIC_RELAXED, __HIP_MEMORY_SCOPE_AGENT);
}
__device__ __forceinline__ void stq_rlx(unsigned long long* p, unsigned long long v) {
  __hip_atomic_store(p, v, __ATOMIC_RELAXED, __HIP_MEMORY_SCOPE_AGENT);
}
__device__ __forceinline__ float tanh_fast(float x) {
  return 1.f - 2.f / (1.f + __expf(2.f * x));
}

__global__ __launch_bounds__(64, 1)
void lstm_pipeline(const _Float16* __restrict__ X0, float* __restrict__ yout,
                   _Float16* __restrict__ ring, int* __restrict__ prod,
                   int* __restrict__ cons,
                   const _Float16* __restrict__ Wperm, const float* __restrict__ gbias) {
  const int l    = blockIdx.x >> 3;
  const int g    = blockIdx.x & 7;
  const int lane = threadIdx.x;
  const int col  = lane & 15;          // batch-in-group (MFMA n / C col)
  const int q8   = lane >> 4;          // k-quad (B) == row-quad (C/D)

  __shared__ _Float16 hbuf[16][40];    // [batch][unit], 80B rows (16B-aligned)
  __shared__ _Float16 xlds[8][16][40]; // chunk x staging, same fragment layout

  // ---- A-frags: A[m=lane&15][k=quad*8+j]; 7 m-tiles x 2 k-halves --------
  h8v afr[7][2];
  f4v bias4[7];
  const _Float16* wp = Wperm + (size_t)l * 7168;
#pragma unroll
  for (int mt = 0; mt < 7; mt++) {
#pragma unroll
    for (int kh = 0; kh < 2; kh++)
      afr[mt][kh] = *(const h8v*)&wp[(mt * 16 + col) * 64 + kh * 32 + q8 * 8];
    bias4[mt] = *(const f4v*)&gbias[l * 112 + mt * 16 + q8 * 4];
  }
  float cst[7] = {0.f, 0.f, 0.f, 0.f, 0.f, 0.f, 0.f};
  h8v hv = {};                         // h B-frag (initial h = 0)
  for (int i = lane; i < 16 * 40; i += 64) (&hbuf[0][0])[i] = (_Float16)0.f;
  // single wave per block -> wave-coherent LDS, no barriers ever

  const unsigned long long* rin =
      (const unsigned long long*)(ring + ((size_t)((l > 0 ? l - 1 : 0) * 8 + g)) * 32768)
      + (size_t)col * 8 + q8 * 2;
  unsigned long long* rout =
      (unsigned long long*)(ring + ((size_t)(l * 8 + g)) * 32768)
      + (size_t)col * 8 + q8 * 2;
  int* pflag  = prod + ((l > 0 ? l - 1 : 0) * 8 + g);
  int* cflagn = cons + ((l < 31 ? l + 1 : 31) * 8 + g);
  const _Float16* x0base = X0 + ((size_t)(g * 16 + col)) * 32 + q8 * 8;

  for (int n = 0; n < 64; n++) {
    if (l > 0)            { while (ld_rlx(pflag)  < n + 1) __builtin_amdgcn_s_sleep(1); }
    if (l < 31 && n >= 8) { while (ld_rlx(cflagn) < n - 7) __builtin_amdgcn_s_sleep(1); }
    asm volatile("" ::: "memory");     // no hoisting loads above the poll

    // stage chunk x into LDS (16B per lane per step; fragment-ready layout)
    if (l == 0) {
#pragma unroll
      for (int tc = 0; tc < 8; tc++) {
        uint4 v = *(const uint4*)(x0base + (size_t)(n * 8 + tc) * 128 * 32);
        *(uint4*)&xlds[tc][col][q8 * 8] = v;
      }
    } else {
      const unsigned long long* base = rin + (size_t)(n & 7) * 8 * 128;
#pragma unroll
      for (int tc = 0; tc < 8; tc++) {
        unsigned long long a = ldq_rlx(base + tc * 128);
        unsigned long long b = ldq_rlx(base + tc * 128 + 1);
        uint4 v = make_uint4((unsigned)a, (unsigned)(a >> 32),
                             (unsigned)b, (unsigned)(b >> 32));
        *(uint4*)&xlds[tc][col][q8 * 8] = v;
      }
    }

#pragma unroll
    for (int tc = 0; tc < 8; tc++) {
      h8v xv = *(const h8v*)&xlds[tc][col][q8 * 8];
      f4v acc[7];
#pragma unroll
      for (int mt = 0; mt < 7; mt++) acc[mt] = bias4[mt];
#pragma unroll
      for (int mt = 0; mt < 7; mt++)
        acc[mt] = __builtin_amdgcn_mfma_f32_16x16x32_f16(afr[mt][0], xv, acc[mt], 0, 0, 0);
#pragma unroll
      for (int mt = 0; mt < 7; mt++)
        acc[mt] = __builtin_amdgcn_mfma_f32_16x16x32_f16(afr[mt][1], hv, acc[mt], 0, 0, 0);
      // elementwise: lane-local — unit u=mt*4+q8, batch=col
#pragma unroll
      for (int mt = 0; mt < 7; mt++) {
        const int u = mt * 4 + q8;
        float si = 1.f / (1.f + __expf(-acc[mt][0]));
        float sf = 1.f / (1.f + __expf(-acc[mt][1]));
        float so = 1.f / (1.f + __expf(-acc[mt][3]));
        float c  = sf * cst[mt] + si * tanh_fast(acc[mt][2]);
        cst[mt] = c;
        float h = so * tanh_fast(c);
        if (u < 25) {
          hbuf[col][u] = (_Float16)h;
          if (l == 31)
            yout[((size_t)(g * 16 + col) * 512 + (n * 8 + tc)) * 25 + u] = h;
        }
      }
      hv = *(const h8v*)&hbuf[col][q8 * 8];   // next-step B-frag == ring value
      if (l < 31) {
        uint4 hb = __builtin_bit_cast(uint4, hv);
        unsigned long long* rp = rout + ((size_t)((n & 7) * 8 + tc)) * 128;
        stq_rlx(rp,     (unsigned long long)hb.x | ((unsigned long long)hb.y << 32));
        stq_rlx(rp + 1, (unsigned long long)hb.z | ((unsigned long long)hb.w << 32));
      }
    }
    asm volatile("s_waitcnt vmcnt(0)" ::: "memory");  // stores at MALL
    if (lane == 0) {
      if (l < 31) st_rlx(&prod[l * 8 + g], n + 1);
      if (l > 0)  st_rlx(&cons[l * 8 + g], n + 1);
    }
  }
}

// =====================================================================
extern "C" void kernel_launch(void* const* d_in, const int* in_sizes, int n_in,
                              void* d_out, int out_size, void* d_ws, size_t ws_size,
                              hipStream_t stream) {
  const float* x     = (const float*)d_in[0];
  const float* cross = (const float*)d_in[1];
  const float* Wq_s = (const float*)d_in[2];  const float* bq_s = (const float*)d_in[3];
  const float* Wk_s = (const float*)d_in[4];  const float* bk_s = (const float*)d_in[5];
  const float* Wv_s = (const float*)d_in[6];  const float* bv_s = (const float*)d_in[7];
  const float* Wo_s = (const float*)d_in[8];  const float* bo_s = (const float*)d_in[9];
  const float* Wq_c = (const float*)d_in[10]; const float* bq_c = (const float*)d_in[11];
  const float* Wk_c = (const float*)d_in[12]; const float* bk_c = (const float*)d_in[13];
  const float* Wv_c = (const float*)d_in[14]; const float* bv_c = (const float*)d_in[15];
  const float* Wo_c = (const float*)d_in[16]; const float* bo_c = (const float*)d_in[17];
  const float* g1 = (const float*)d_in[18]; const float* b1 = (const float*)d_in[19];
  const float* g2 = (const float*)d_in[20]; const float* b2 = (const float*)d_in[21];
  const float* g3 = (const float*)d_in[22]; const float* b3 = (const float*)d_in[23];
  const float* Wih = (const float*)d_in[24];
  const float* Whh = (const float*)d_in[25];
  const float* bih = (const float*)d_in[26];
  const float* bhh = (const float*)d_in[27];
  const float* Wc  = (const float*)d_in[28]; const float* bc = (const float*)d_in[29];
  float* out = (float*)d_out;
  float* ws  = (float*)d_ws;

  // ---- workspace (floats); time-multiplexed (R6 map) --------------------
  constexpr size_t A  = 1638400;    // 3200*512
  constexpr size_t C6 = 6291456;    // 12288*512
  float* x1    = ws;
  float* Qc    = ws + A;
  // self phase
  float* Qs    = ws + 2 * A;
  float* Ks    = ws + 3 * A;
  float* Vs    = ws + 4 * A;
  float* attns = ws + 5 * A;
  float* tmp   = ws + 6 * A;
  float* Ps    = ws + 7 * A;
  // cross phase
  float* Kc    = ws + 2 * A;
  float* Vc    = ws + 2 * A + C6;
  float* attnc = ws + 2 * A + 2 * C6;
  float* Pc    = attnc + A;
  float* tmp2  = ws + 6 * A;
  float* x2    = ws + 3 * A;
  // lstm / post
  _Float16* X0b  = (_Float16*)(ws + 4 * A);      // 2,097,152 halves
  float*    youtb = ws + 5 * A;                  // [128][512][25] fp32
  _Float16* ringb = (_Float16*)(ws + 6 * A);     // 8,388,608 halves
  _Float16* WpermB = (_Float16*)(ws + 14100000); // 229,376 halves
  float*    gbiasB = ws + 14300000;              // 3,584 floats
  float* ytb   = ws + 2 * A;
  float* fy    = ws + 5 * A;                     // after youtb dead
  _Float16* WTall = (_Float16*)(ws + 20000000);
  int* ctr = (int*)(ws + 21179648);

  dim3 blk(256);
  WPtrs wpq;
  wpq.p[0] = Wq_s; wpq.p[1] = Wk_s; wpq.p[2] = Wv_s; wpq.p[3] = Wo_s;
  wpq.p[4] = Wq_c; wpq.p[5] = Wk_c; wpq.p[6] = Wv_c; wpq.p[7] = Wo_c;
  wpq.p[8] = Wc;
  prep_weights<<<dim3(16, 16, 9), blk, 0, stream>>>(wpq, WTall);
  hipMemsetAsync(ctr, 0, 1024 * sizeof(int), stream);
  _Float16* WT[9];
  for (int i = 0; i < 9; i++) WT[i] = WTall + (size_t)i * 262144;

  // ---- self attention ----
  gemm3<<<dim3(24, 50), blk, 0, stream>>>(x, WT[0], WT[1], WT[2],
                                          bq_s, bk_s, bv_s, Qs, Ks, Vs, 3200);
  attn_scores<25><<<dim3(8, 128), blk, 0, stream>>>(Qs, Ks, Ps);
  attn_out<25><<<dim3(8, 128), blk, 0, stream>>>(Ps, Vs, attns);
  gemm3<<<dim3(8, 50), blk, 0, stream>>>(attns, WT[3], WT[3], WT[3],
                                         bo_s, bo_s, bo_s, tmp, tmp, tmp, 3200);
  add_ln<<<3200, 128, 0, stream>>>(x, tmp, g1, b1, x1);
  // ---- cross attention ----
  gemm3<<<dim3(8, 50), blk, 0, stream>>>(x1, WT[4], WT[4], WT[4],
                                         bq_c, bq_c, bq_c, Qc, Qc, Qc, 3200);
  gemm3<<<dim3(16, 192), blk, 0, stream>>>(cross, WT[5], WT[6], WT[6],
                                           bk_c, bv_c, bv_c, Kc, Vc, Vc, 12288);
  attn_scores<96><<<dim3(8, 128), blk, 0, stream>>>(Qc, Kc, Pc);
  attn_out<96><<<dim3(8, 128), blk, 0, stream>>>(Pc, Vc, attnc);
  gemm3<<<dim3(8, 50), blk, 0, stream>>>(attnc, WT[7], WT[7], WT[7],
                                         bo_c, bo_c, bo_c, tmp2, tmp2, tmp2, 3200);
  add_ln<<<3200, 128, 0, stream>>>(x1, tmp2, g2, b2, x2);
  // ---- LSTM over feature axis (persistent MFMA pipeline) ----
  prep_lstm_w<<<32, 256, 0, stream>>>(Wih, Whh, bih, bhh, WpermB, gbiasB);
  prep_x0<<<128, 256, 0, stream>>>(x2, X0b);
  lstm_pipeline<<<256, 64, 0, stream>>>(X0b, youtb, ringb, ctr, ctr + 256,
                                        WpermB, gbiasB);
  // ---- pointwise conv over channels + final LN ----
  transpose_dl<<<128, 256, 0, stream>>>(youtb, ytb);
  gemm3<<<dim3(8, 50), blk, 0, stream>>>(ytb, WT[8], WT[8], WT[8],
                                         bc, bc, bc, fy, fy, fy, 3200);
  add_ln<<<3200, 128, 0, stream>>>(x2, fy, g3, b3, out);
}

// Round 8
// 1542.452 us; speedup vs baseline: 1.1531x; 1.1531x over previous
//
#include <hip/hip_runtime.h>

// =====================================================================
// DecoderLayer: selfMHA -> LN -> crossMHA -> LN -> 32xLSTM(pipelined)
//               -> pointwise conv -> LN
// Round 8: LSTM pipeline re-blocked: 64 blocks x 4 waves; wave = layer.
//          24/31 layer boundaries via LDS rings (acquire/release WG flags);
//          7 quad boundaries via batched sc1 asm loads/stores at MALL.
//          Per-wave MFMA math identical to R6/R7 (verified).
// =====================================================================

#define EPS_LN 1e-5f

typedef _Float16 h8v __attribute__((ext_vector_type(8)));
typedef float    f4v __attribute__((ext_vector_type(4)));
typedef unsigned int u4v __attribute__((ext_vector_type(4)));

// ---------------- fused weight prep: 8 transposes + 1 straight cvt -------
struct WPtrs { const float* p[9]; };

__global__ __launch_bounds__(256)
void prep_weights(WPtrs w, _Float16* __restrict__ dst) {
  __shared__ float tile[32][33];
  const int z = blockIdx.z;
  const int tx = threadIdx.x & 31, ty = threadIdx.x >> 5;
  const int bx = blockIdx.x, by = blockIdx.y;
  const float* in = w.p[z];
  _Float16* outp = dst + (size_t)z * 262144;
  if (z < 8) {
#pragma unroll
    for (int i = 0; i < 4; i++)
      tile[ty + i * 8][tx] = in[(size_t)(by * 32 + ty + i * 8) * 512 + bx * 32 + tx];
    __syncthreads();
#pragma unroll
    for (int i = 0; i < 4; i++)
      outp[(size_t)(bx * 32 + ty + i * 8) * 512 + by * 32 + tx] = (_Float16)tile[tx][ty + i * 8];
  } else {
#pragma unroll
    for (int i = 0; i < 4; i++) {
      size_t off = (size_t)(by * 32 + ty + i * 8) * 512 + bx * 32 + tx;
      outp[off] = (_Float16)in[off];
    }
  }
}

// ---------------- f16 MFMA GEMM, fp32 A staged+converted in LDS ----------
__global__ __launch_bounds__(256)
void gemm3(const float* __restrict__ A,
           const _Float16* __restrict__ BT0, const _Float16* __restrict__ BT1,
           const _Float16* __restrict__ BT2,
           const float* __restrict__ bias0, const float* __restrict__ bias1,
           const float* __restrict__ bias2,
           float* __restrict__ C0, float* __restrict__ C1, float* __restrict__ C2,
           int M) {
  __shared__ _Float16 Asld[64 * 40];
  __shared__ _Float16 Bsld[64 * 40];
  const int t = threadIdx.x;
  const int which = blockIdx.x >> 3;
  const int n0 = (blockIdx.x & 7) * 64;
  const int m0 = blockIdx.y * 64;
  const _Float16* BT = (which == 0) ? BT0 : (which == 1) ? BT1 : BT2;
  const float* bias  = (which == 0) ? bias0 : (which == 1) ? bias1 : bias2;
  float* C           = (which == 0) ? C0 : (which == 1) ? C1 : C2;

  const int r = t >> 2, q = t & 3;
  const int w = t >> 6;
  const int lane = t & 63;
  const int lm = lane & 15, q8 = lane >> 4;

  f4v acc[4] = {};
  for (int k0 = 0; k0 < 512; k0 += 32) {
    __syncthreads();
    float4 f0 = *(const float4*)&A[(size_t)(m0 + r) * 512 + k0 + q * 8];
    float4 f1 = *(const float4*)&A[(size_t)(m0 + r) * 512 + k0 + q * 8 + 4];
    h8v hvv = {(_Float16)f0.x, (_Float16)f0.y, (_Float16)f0.z, (_Float16)f0.w,
               (_Float16)f1.x, (_Float16)f1.y, (_Float16)f1.z, (_Float16)f1.w};
    *(h8v*)&Asld[r * 40 + q * 8] = hvv;
    *(uint4*)&Bsld[r * 40 + q * 8] = *(const uint4*)&BT[(size_t)(n0 + r) * 512 + k0 + q * 8];
    __syncthreads();
    h8v a = *(const h8v*)&Asld[(w * 16 + lm) * 40 + q8 * 8];
#pragma unroll
    for (int nt = 0; nt < 4; nt++) {
      h8v b = *(const h8v*)&Bsld[(nt * 16 + lm) * 40 + q8 * 8];
      acc[nt] = __builtin_amdgcn_mfma_f32_16x16x32_f16(a, b, acc[nt], 0, 0, 0);
    }
  }
#pragma unroll
  for (int nt = 0; nt < 4; nt++) {
    int gn = n0 + nt * 16 + lm;
    float bv = bias[gn];
#pragma unroll
    for (int rg = 0; rg < 4; rg++) {
      int gm = m0 + w * 16 + q8 * 4 + rg;
      C[(size_t)gm * 512 + gn] = acc[nt][rg] + bv;
    }
  }
}

// ---------------- attention: scores then softmax+PV, per (b,h) -----------
template <int S>
__global__ __launch_bounds__(256)
void attn_scores(const float* __restrict__ Q, const float* __restrict__ K,
                 float* __restrict__ P) {
  __shared__ float Qs[25][64];
  __shared__ float Ks[S][65];
  const int h = blockIdx.x, b = blockIdx.y, t = threadIdx.x;
  for (int idx = t; idx < 25 * 64; idx += 256) {
    int l = idx >> 6, e = idx & 63;
    Qs[l][e] = Q[(b * 25 + l) * 512 + h * 64 + e];
  }
  for (int idx = t; idx < S * 64; idx += 256) {
    int s = idx >> 6, e = idx & 63;
    Ks[s][e] = K[(b * S + s) * 512 + h * 64 + e];
  }
  __syncthreads();
  float* Pb = P + (size_t)(b * 8 + h) * 25 * S;
  for (int idx = t; idx < 25 * S; idx += 256) {
    int l = idx / S, s = idx % S;
    float acc = 0.f;
#pragma unroll
    for (int e = 0; e < 64; e++) acc += Qs[l][e] * Ks[s][e];
    Pb[idx] = acc * 0.125f;
  }
}

template <int S>
__global__ __launch_bounds__(256)
void attn_out(const float* __restrict__ P, const float* __restrict__ V,
              float* __restrict__ O) {
  __shared__ float Ps[25][S];
  __shared__ float Vs[S][64];
  const int h = blockIdx.x, b = blockIdx.y, t = threadIdx.x;
  const float* Pb = P + (size_t)(b * 8 + h) * 25 * S;
  for (int idx = t; idx < 25 * S; idx += 256) Ps[idx / S][idx % S] = Pb[idx];
  for (int idx = t; idx < S * 64; idx += 256) {
    int s = idx >> 6, e = idx & 63;
    Vs[s][e] = V[(b * S + s) * 512 + h * 64 + e];
  }
  __syncthreads();
  if (t < 25) {
    float mx = -1e30f;
    for (int s = 0; s < S; s++) mx = fmaxf(mx, Ps[t][s]);
    float sum = 0.f;
    for (int s = 0; s < S; s++) { float p = __expf(Ps[t][s] - mx); Ps[t][s] = p; sum += p; }
    float r = 1.f / sum;
    for (int s = 0; s < S; s++) Ps[t][s] *= r;
  }
  __syncthreads();
  for (int idx = t; idx < 25 * 64; idx += 256) {
    int l = idx >> 6, e = idx & 63;
    float acc = 0.f;
    for (int s = 0; s < S; s++) acc += Ps[l][s] * Vs[s][e];
    O[(b * 25 + l) * 512 + h * 64 + e] = acc;
  }
}

// ---------------- fused residual-add + LayerNorm (rows of 512) -----------
__global__ __launch_bounds__(128)
void add_ln(const float* __restrict__ a, const float* __restrict__ b,
            const float* __restrict__ gw, const float* __restrict__ bw,
            float* __restrict__ out) {
  const int row = blockIdx.x, t = threadIdx.x;
  float4 va = ((const float4*)(a + (size_t)row * 512))[t];
  float4 vb = ((const float4*)(b + (size_t)row * 512))[t];
  float4 v = make_float4(va.x + vb.x, va.y + vb.y, va.z + vb.z, va.w + vb.w);
  float s = v.x + v.y + v.z + v.w;
  float q = v.x * v.x + v.y * v.y + v.z * v.z + v.w * v.w;
#pragma unroll
  for (int off = 32; off > 0; off >>= 1) {
    s += __shfl_down(s, off);
    q += __shfl_down(q, off);
  }
  __shared__ float red[4];
  if ((t & 63) == 0) { red[(t >> 6) * 2] = s; red[(t >> 6) * 2 + 1] = q; }
  __syncthreads();
  float S_ = red[0] + red[2], Q_ = red[1] + red[3];
  float mean = S_ * (1.f / 512.f);
  float var  = Q_ * (1.f / 512.f) - mean * mean;
  float inv  = rsqrtf(var + EPS_LN);
  float4 g4 = ((const float4*)gw)[t];
  float4 b4 = ((const float4*)bw)[t];
  float4 o;
  o.x = (v.x - mean) * inv * g4.x + b4.x;
  o.y = (v.y - mean) * inv * g4.y + b4.y;
  o.z = (v.z - mean) * inv * g4.z + b4.z;
  o.w = (v.w - mean) * inv * g4.w + b4.w;
  ((float4*)(out + (size_t)row * 512))[t] = o;
}

// ---------------- transposes / LSTM preps --------------------------------
__global__ void transpose_dl(const float* __restrict__ in, float* __restrict__ outp) {
  const int b = blockIdx.x, t = threadIdx.x;
  for (int idx = t; idx < 25 * 512; idx += 256) {
    int l2 = idx / 512, c = idx % 512;
    outp[((size_t)b * 25 + l2) * 512 + c] = in[((size_t)b * 512 + c) * 25 + l2];
  }
}

// Wperm[l][112][64]: row r=4u+gate, k=0..24 -> Wih, k=32..56 -> Whh, else 0.
__global__ __launch_bounds__(256)
void prep_lstm_w(const float* __restrict__ Wih, const float* __restrict__ Whh,
                 const float* __restrict__ bih, const float* __restrict__ bhh,
                 _Float16* __restrict__ Wperm, float* __restrict__ gbias) {
  const int l = blockIdx.x, t = threadIdx.x;
  for (int idx = t; idx < 112 * 64; idx += 256) {
    int r = idx >> 6, k = idx & 63;
    int u = r >> 2, gi = r & 3;
    float v = 0.f;
    if (u < 25) {
      if (k < 25) v = Wih[((size_t)l * 100 + gi * 25 + u) * 25 + k];
      else if (k >= 32 && k < 57) v = Whh[((size_t)l * 100 + gi * 25 + u) * 25 + (k - 32)];
    }
    Wperm[(size_t)l * 7168 + idx] = (_Float16)v;
  }
  for (int idx = t; idx < 112; idx += 256) {
    int u = idx >> 2, gi = idx & 3;
    float v = 0.f;
    if (u < 25) v = bih[l * 100 + gi * 25 + u] + bhh[l * 100 + gi * 25 + u];
    gbias[l * 112 + idx] = v;
  }
}

// X0[t=512][b=128][32] f16 from x2[b][25][512]
__global__ __launch_bounds__(256)
void prep_x0(const float* __restrict__ x2, _Float16* __restrict__ X0) {
  __shared__ float tile[25][516];
  const int b = blockIdx.x, t = threadIdx.x;
  for (int idx = t; idx < 25 * 512; idx += 256) {
    int u = idx >> 9, d = idx & 511;
    tile[u][d] = x2[((size_t)b * 25 + u) * 512 + d];
  }
  __syncthreads();
  for (int idx = t; idx < 512 * 32; idx += 256) {
    int d = idx >> 5, u = idx & 31;
    X0[((size_t)d * 128 + b) * 32 + u] = (u < 25) ? (_Float16)tile[u][d] : (_Float16)0.f;
  }
}

// ---------------- MFMA persistent LSTM, wave-per-layer in-block pipeline --
__device__ __forceinline__ int ld_rlx(int* p) {
  return __hip_atomic_load(p, __ATOMIC_RELAXED, __HIP_MEMORY_SCOPE_AGENT);
}
__device__ __forceinline__ void st_rlx(int* p, int v) {
  __hip_atomic_store(p, v, __ATOMIC_RELAXED, __HIP_MEMORY_SCOPE_AGENT);
}
__device__ __forceinline__ int ldw_acq(int* p) {
  return __hip_atomic_load(p, __ATOMIC_ACQUIRE, __HIP_MEMORY_SCOPE_WORKGROUP);
}
__device__ __forceinline__ void stw_rel(int* p, int v) {
  __hip_atomic_store(p, v, __ATOMIC_RELEASE, __HIP_MEMORY_SCOPE_WORKGROUP);
}
__device__ __forceinline__ float tanh_fast(float x) {
  return 1.f - 2.f / (1.f + __expf(2.f * x));
}
// 8 x 16B device-coherent loads, one batch, one wait. base points 4096 B
// into the chunk region so imm offsets span [-4096, 3072].
__device__ __forceinline__ void mall_load8(u4v x[8], const _Float16* base4096) {
  unsigned long long a = (unsigned long long)base4096;
  asm volatile(
      "global_load_dwordx4 %0, %8, off offset:-4096 sc1\n\t"
      "global_load_dwordx4 %1, %8, off offset:-3072 sc1\n\t"
      "global_load_dwordx4 %2, %8, off offset:-2048 sc1\n\t"
      "global_load_dwordx4 %3, %8, off offset:-1024 sc1\n\t"
      "global_load_dwordx4 %4, %8, off sc1\n\t"
      "global_load_dwordx4 %5, %8, off offset:1024 sc1\n\t"
      "global_load_dwordx4 %6, %8, off offset:2048 sc1\n\t"
      "global_load_dwordx4 %7, %8, off offset:3072 sc1\n\t"
      "s_waitcnt vmcnt(0)"
      : "=&v"(x[0]), "=&v"(x[1]), "=&v"(x[2]), "=&v"(x[3]),
        "=&v"(x[4]), "=&v"(x[5]), "=&v"(x[6]), "=&v"(x[7])
      : "v"(a)
      : "memory");
}
__device__ __forceinline__ void mall_store16(_Float16* p, u4v v) {
  unsigned long long a = (unsigned long long)p;
  asm volatile("global_store_dwordx4 %0, %1, off sc1" :: "v"(a), "v"(v) : "memory");
}

// grid = 64 blocks (lq 0..7 x g 0..7), 256 threads = 4 waves; wave w is
// layer l = lq*4+w for batch group g (16 batches). Intra-block boundaries:
// LDS ring (2-chunk deep) + WG acquire/release flags. Quad boundaries:
// MALL ring (8-chunk deep) + relaxed agent flags after vmcnt drains.
__global__ __launch_bounds__(256, 1)
void lstm_pipeline(const _Float16* __restrict__ X0, float* __restrict__ yout,
                   _Float16* __restrict__ ring, int* __restrict__ prod,
                   int* __restrict__ cons,
                   const _Float16* __restrict__ Wperm, const float* __restrict__ gbias) {
  const int lq   = blockIdx.x >> 3;
  const int g    = blockIdx.x & 7;
  const int w    = threadIdx.x >> 6;   // wave in block = layer offset
  const int l    = lq * 4 + w;
  const int lane = threadIdx.x & 63;
  const int col  = lane & 15;          // batch-in-group
  const int q8   = lane >> 4;          // k-quad (B) == row-quad (C/D)

  __shared__ _Float16 lring[3 * 16 * 512];  // 3 boundaries x 16 slots x (16b x 32u)
  __shared__ _Float16 hbufA[4 * 16 * 40];   // per-wave h scratch
  __shared__ int prodL[3], consL[3];

  _Float16* hbufW = hbufA + w * 640;
  for (int i = lane; i < 640; i += 64) hbufW[i] = (_Float16)0.f;
  if (threadIdx.x < 3) { prodL[threadIdx.x] = 0; consL[threadIdx.x] = 0; }
  __syncthreads();                     // the ONLY block barrier

  // ---- per-wave A-frags / bias / state ----
  h8v afr[7][2];
  f4v bias4[7];
  const _Float16* wp = Wperm + (size_t)l * 7168;
#pragma unroll
  for (int mt = 0; mt < 7; mt++) {
#pragma unroll
    for (int kh = 0; kh < 2; kh++)
      afr[mt][kh] = *(const h8v*)&wp[(mt * 16 + col) * 64 + kh * 32 + q8 * 8];
    bias4[mt] = *(const f4v*)&gbias[l * 112 + mt * 16 + q8 * 4];
  }
  float cst[7] = {0.f, 0.f, 0.f, 0.f, 0.f, 0.f, 0.f};
  h8v hv = {};

  // MALL ring region r (r = producer's lq): halves base (r*8+g)*32768
  _Float16* rout = (lq < 7) ? ring + ((size_t)(lq * 8 + g)) * 32768 : nullptr;
  const _Float16* rin = (lq > 0) ? ring + ((size_t)((lq - 1) * 8 + g)) * 32768 : nullptr;
  int* mall_prod_in  = prod + ((lq > 0 ? lq - 1 : 0) * 8 + g);  // wave0 polls
  int* mall_cons_in  = cons + ((lq > 0 ? lq - 1 : 0) * 8 + g);  // wave0 publishes
  int* mall_prod_out = prod + ((lq < 7 ? lq : 0) * 8 + g);      // wave3 publishes
  int* mall_cons_out = cons + ((lq < 7 ? lq : 0) * 8 + g);      // wave3 polls

  for (int n = 0; n < 64; n++) {
    // ---- acquire input chunk n ----
    u4v xq[8];
    if (w == 0) {
      if (lq == 0) {
#pragma unroll
        for (int tc = 0; tc < 8; tc++)
          xq[tc] = *(const u4v*)&X0[((size_t)(n * 8 + tc) * 128 + g * 16 + col) * 32 + q8 * 8];
      } else {
        while (ld_rlx(mall_prod_in) < n + 1) __builtin_amdgcn_s_sleep(1);
        asm volatile("" ::: "memory");
        const _Float16* cb = rin + (size_t)(n & 7) * 4096 + col * 32 + q8 * 8 + 2048;
        mall_load8(xq, cb);
        if (lane == 0) st_rlx(mall_cons_in, n + 1);   // slot freed (data in regs)
      }
    } else {
      while (ldw_acq(&prodL[w - 1]) < n + 1) __builtin_amdgcn_s_sleep(1);
    }
    // ---- output ring space ----
    if (w < 3) {
      if (n >= 2) while (ldw_acq(&consL[w]) < n - 1) __builtin_amdgcn_s_sleep(1);
    } else if (lq < 7) {
      if (n >= 8) { while (ld_rlx(mall_cons_out) < n - 7) __builtin_amdgcn_s_sleep(1); }
      asm volatile("" ::: "memory");
    }

    // ---- 8 timesteps ----
#pragma unroll
    for (int tc = 0; tc < 8; tc++) {
      const int tg = n * 8 + tc;
      h8v xv;
      if (w == 0)
        xv = __builtin_bit_cast(h8v, xq[tc]);
      else
        xv = *(const h8v*)&lring[((w - 1) * 16 + (tg & 15)) * 512 + col * 32 + q8 * 8];
      f4v acc[7];
#pragma unroll
      for (int mt = 0; mt < 7; mt++) acc[mt] = bias4[mt];
#pragma unroll
      for (int mt = 0; mt < 7; mt++)
        acc[mt] = __builtin_amdgcn_mfma_f32_16x16x32_f16(afr[mt][0], xv, acc[mt], 0, 0, 0);
#pragma unroll
      for (int mt = 0; mt < 7; mt++)
        acc[mt] = __builtin_amdgcn_mfma_f32_16x16x32_f16(afr[mt][1], hv, acc[mt], 0, 0, 0);
#pragma unroll
      for (int mt = 0; mt < 7; mt++) {
        const int u = mt * 4 + q8;
        float si = 1.f / (1.f + __expf(-acc[mt][0]));
        float sf = 1.f / (1.f + __expf(-acc[mt][1]));
        float so = 1.f / (1.f + __expf(-acc[mt][3]));
        float c  = sf * cst[mt] + si * tanh_fast(acc[mt][2]);
        cst[mt] = c;
        float h = so * tanh_fast(c);
        if (u < 25) {
          hbufW[col * 40 + u] = (_Float16)h;
          if (l == 31)
            yout[((size_t)(g * 16 + col) * 512 + tg) * 25 + u] = h;
        }
      }
      hv = *(const h8v*)&hbufW[col * 40 + q8 * 8];   // next-step B-frag
      if (w < 3) {
        *(h8v*)&lring[(w * 16 + (tg & 15)) * 512 + col * 32 + q8 * 8] = hv;
      } else if (lq < 7) {
        mall_store16(rout + (size_t)(n & 7) * 4096 + (size_t)tc * 512 + col * 32 + q8 * 8,
                     __builtin_bit_cast(u4v, hv));
      }
    }

    // ---- publish ----
    if (w < 3) {
      if (lane == 0) stw_rel(&prodL[w], n + 1);      // release: lgkm drained
    } else if (lq < 7) {
      asm volatile("s_waitcnt vmcnt(0)" ::: "memory");
      if (lane == 0) st_rlx(mall_prod_out, n + 1);
    }
    if (w > 0) {
      if (lane == 0) stw_rel(&consL[w - 1], n + 1);  // chunk n fully read
    }
  }
}

// =====================================================================
extern "C" void kernel_launch(void* const* d_in, const int* in_sizes, int n_in,
                              void* d_out, int out_size, void* d_ws, size_t ws_size,
                              hipStream_t stream) {
  const float* x     = (const float*)d_in[0];
  const float* cross = (const float*)d_in[1];
  const float* Wq_s = (const float*)d_in[2];  const float* bq_s = (const float*)d_in[3];
  const float* Wk_s = (const float*)d_in[4];  const float* bk_s = (const float*)d_in[5];
  const float* Wv_s = (const float*)d_in[6];  const float* bv_s = (const float*)d_in[7];
  const float* Wo_s = (const float*)d_in[8];  const float* bo_s = (const float*)d_in[9];
  const float* Wq_c = (const float*)d_in[10]; const float* bq_c = (const float*)d_in[11];
  const float* Wk_c = (const float*)d_in[12]; const float* bk_c = (const float*)d_in[13];
  const float* Wv_c = (const float*)d_in[14]; const float* bv_c = (const float*)d_in[15];
  const float* Wo_c = (const float*)d_in[16]; const float* bo_c = (const float*)d_in[17];
  const float* g1 = (const float*)d_in[18]; const float* b1 = (const float*)d_in[19];
  const float* g2 = (const float*)d_in[20]; const float* b2 = (const float*)d_in[21];
  const float* g3 = (const float*)d_in[22]; const float* b3 = (const float*)d_in[23];
  const float* Wih = (const float*)d_in[24];
  const float* Whh = (const float*)d_in[25];
  const float* bih = (const float*)d_in[26];
  const float* bhh = (const float*)d_in[27];
  const float* Wc  = (const float*)d_in[28]; const float* bc = (const float*)d_in[29];
  float* out = (float*)d_out;
  float* ws  = (float*)d_ws;

  // ---- workspace (floats); time-multiplexed (R7 map; ring now smaller) --
  constexpr size_t A  = 1638400;    // 3200*512
  constexpr size_t C6 = 6291456;    // 12288*512
  float* x1    = ws;
  float* Qc    = ws + A;
  float* Qs    = ws + 2 * A;
  float* Ks    = ws + 3 * A;
  float* Vs    = ws + 4 * A;
  float* attns = ws + 5 * A;
  float* tmp   = ws + 6 * A;
  float* Ps    = ws + 7 * A;
  float* Kc    = ws + 2 * A;
  float* Vc    = ws + 2 * A + C6;
  float* attnc = ws + 2 * A + 2 * C6;
  float* Pc    = attnc + A;
  float* tmp2  = ws + 6 * A;
  float* x2    = ws + 3 * A;
  _Float16* X0b  = (_Float16*)(ws + 4 * A);      // 2,097,152 halves
  float*    youtb = ws + 5 * A;                  // [128][512][25] fp32
  _Float16* ringb = (_Float16*)(ws + 6 * A);     // 7*8*32768 = 1,835,008 halves
  _Float16* WpermB = (_Float16*)(ws + 14100000); // 229,376 halves
  float*    gbiasB = ws + 14300000;              // 3,584 floats
  float* ytb   = ws + 2 * A;
  float* fy    = ws + 5 * A;                     // after youtb dead
  _Float16* WTall = (_Float16*)(ws + 20000000);
  int* ctr = (int*)(ws + 21179648);

  dim3 blk(256);
  WPtrs wpq;
  wpq.p[0] = Wq_s; wpq.p[1] = Wk_s; wpq.p[2] = Wv_s; wpq.p[3] = Wo_s;
  wpq.p[4] = Wq_c; wpq.p[5] = Wk_c; wpq.p[6] = Wv_c; wpq.p[7] = Wo_c;
  wpq.p[8] = Wc;
  prep_weights<<<dim3(16, 16, 9), blk, 0, stream>>>(wpq, WTall);
  hipMemsetAsync(ctr, 0, 1024 * sizeof(int), stream);
  _Float16* WT[9];
  for (int i = 0; i < 9; i++) WT[i] = WTall + (size_t)i * 262144;

  // ---- self attention ----
  gemm3<<<dim3(24, 50), blk, 0, stream>>>(x, WT[0], WT[1], WT[2],
                                          bq_s, bk_s, bv_s, Qs, Ks, Vs, 3200);
  attn_scores<25><<<dim3(8, 128), blk, 0, stream>>>(Qs, Ks, Ps);
  attn_out<25><<<dim3(8, 128), blk, 0, stream>>>(Ps, Vs, attns);
  gemm3<<<dim3(8, 50), blk, 0, stream>>>(attns, WT[3], WT[3], WT[3],
                                         bo_s, bo_s, bo_s, tmp, tmp, tmp, 3200);
  add_ln<<<3200, 128, 0, stream>>>(x, tmp, g1, b1, x1);
  // ---- cross attention ----
  gemm3<<<dim3(8, 50), blk, 0, stream>>>(x1, WT[4], WT[4], WT[4],
                                         bq_c, bq_c, bq_c, Qc, Qc, Qc, 3200);
  gemm3<<<dim3(16, 192), blk, 0, stream>>>(cross, WT[5], WT[6], WT[6],
                                           bk_c, bv_c, bv_c, Kc, Vc, Vc, 12288);
  attn_scores<96><<<dim3(8, 128), blk, 0, stream>>>(Qc, Kc, Pc);
  attn_out<96><<<dim3(8, 128), blk, 0, stream>>>(Pc, Vc, attnc);
  gemm3<<<dim3(8, 50), blk, 0, stream>>>(attnc, WT[7], WT[7], WT[7],
                                         bo_c, bo_c, bo_c, tmp2, tmp2, tmp2, 3200);
  add_ln<<<3200, 128, 0, stream>>>(x1, tmp2, g2, b2, x2);
  // ---- LSTM over feature axis (wave-per-layer persistent pipeline) ----
  prep_lstm_w<<<32, 256, 0, stream>>>(Wih, Whh, bih, bhh, WpermB, gbiasB);
  prep_x0<<<128, 256, 0, stream>>>(x2, X0b);
  lstm_pipeline<<<64, 256, 0, stream>>>(X0b, youtb, ringb, ctr, ctr + 256,
                                        WpermB, gbiasB);
  // ---- pointwise conv over channels + final LN ----
  transpose_dl<<<128, 256, 0, stream>>>(youtb, ytb);
  gemm3<<<dim3(8, 50), blk, 0, stream>>>(ytb, WT[8], WT[8], WT[8],
                                         bc, bc, bc, fy, fy, fy, 3200);
  add_ln<<<3200, 128, 0, stream>>>(x2, fy, g3, b3, out);
}

// Round 9
// 1038.880 us; speedup vs baseline: 1.7120x; 1.4847x over previous
//
#include <hip/hip_runtime.h>

// =====================================================================
// DecoderLayer: selfMHA -> LN -> crossMHA -> LN -> 32xLSTM(pipelined)
//               -> pointwise conv -> LN
// Round 9: back to R5's proven fdot2 LSTM (857us) with its measured
//          overheads fixed: f16 fragment-layout ring (1 vector load/thread
//          staging, 2B f16 producer stores) and the x-part of all 8 steps
//          precomputed densely before the serial h-recurrence loop.
// =====================================================================

#define EPS_LN 1e-5f

typedef _Float16 h2v __attribute__((ext_vector_type(2)));
typedef _Float16 h8v __attribute__((ext_vector_type(8)));
typedef float    f4v __attribute__((ext_vector_type(4)));

#if defined(__has_builtin)
#if __has_builtin(__builtin_amdgcn_fdot2)
#define HAVE_FDOT2 1
#endif
#endif

__device__ __forceinline__ float fdot2(h2v a, h2v b, float c) {
#ifdef HAVE_FDOT2
  return __builtin_amdgcn_fdot2(a, b, c, false);
#else
  return c + (float)a.x * (float)b.x + (float)a.y * (float)b.y;
#endif
}
__device__ __forceinline__ h2v bch2(unsigned int u) {
  return __builtin_bit_cast(h2v, u);
}

// ---------------- fused weight prep: 8 transposes + 1 straight cvt -------
struct WPtrs { const float* p[9]; };

__global__ __launch_bounds__(256)
void prep_weights(WPtrs w, _Float16* __restrict__ dst) {
  __shared__ float tile[32][33];
  const int z = blockIdx.z;
  const int tx = threadIdx.x & 31, ty = threadIdx.x >> 5;
  const int bx = blockIdx.x, by = blockIdx.y;
  const float* in = w.p[z];
  _Float16* outp = dst + (size_t)z * 262144;
  if (z < 8) {
#pragma unroll
    for (int i = 0; i < 4; i++)
      tile[ty + i * 8][tx] = in[(size_t)(by * 32 + ty + i * 8) * 512 + bx * 32 + tx];
    __syncthreads();
#pragma unroll
    for (int i = 0; i < 4; i++)
      outp[(size_t)(bx * 32 + ty + i * 8) * 512 + by * 32 + tx] = (_Float16)tile[tx][ty + i * 8];
  } else {
#pragma unroll
    for (int i = 0; i < 4; i++) {
      size_t off = (size_t)(by * 32 + ty + i * 8) * 512 + bx * 32 + tx;
      outp[off] = (_Float16)in[off];
    }
  }
}

// ---------------- f16 MFMA GEMM, fp32 A staged+converted in LDS ----------
__global__ __launch_bounds__(256)
void gemm3(const float* __restrict__ A,
           const _Float16* __restrict__ BT0, const _Float16* __restrict__ BT1,
           const _Float16* __restrict__ BT2,
           const float* __restrict__ bias0, const float* __restrict__ bias1,
           const float* __restrict__ bias2,
           float* __restrict__ C0, float* __restrict__ C1, float* __restrict__ C2,
           int M) {
  __shared__ _Float16 Asld[64 * 40];
  __shared__ _Float16 Bsld[64 * 40];
  const int t = threadIdx.x;
  const int which = blockIdx.x >> 3;
  const int n0 = (blockIdx.x & 7) * 64;
  const int m0 = blockIdx.y * 64;
  const _Float16* BT = (which == 0) ? BT0 : (which == 1) ? BT1 : BT2;
  const float* bias  = (which == 0) ? bias0 : (which == 1) ? bias1 : bias2;
  float* C           = (which == 0) ? C0 : (which == 1) ? C1 : C2;

  const int r = t >> 2, q = t & 3;
  const int w = t >> 6;
  const int lane = t & 63;
  const int lm = lane & 15, q8 = lane >> 4;

  f4v acc[4] = {};
  for (int k0 = 0; k0 < 512; k0 += 32) {
    __syncthreads();
    float4 f0 = *(const float4*)&A[(size_t)(m0 + r) * 512 + k0 + q * 8];
    float4 f1 = *(const float4*)&A[(size_t)(m0 + r) * 512 + k0 + q * 8 + 4];
    h8v hvv = {(_Float16)f0.x, (_Float16)f0.y, (_Float16)f0.z, (_Float16)f0.w,
               (_Float16)f1.x, (_Float16)f1.y, (_Float16)f1.z, (_Float16)f1.w};
    *(h8v*)&Asld[r * 40 + q * 8] = hvv;
    *(uint4*)&Bsld[r * 40 + q * 8] = *(const uint4*)&BT[(size_t)(n0 + r) * 512 + k0 + q * 8];
    __syncthreads();
    h8v a = *(const h8v*)&Asld[(w * 16 + lm) * 40 + q8 * 8];
#pragma unroll
    for (int nt = 0; nt < 4; nt++) {
      h8v b = *(const h8v*)&Bsld[(nt * 16 + lm) * 40 + q8 * 8];
      acc[nt] = __builtin_amdgcn_mfma_f32_16x16x32_f16(a, b, acc[nt], 0, 0, 0);
    }
  }
#pragma unroll
  for (int nt = 0; nt < 4; nt++) {
    int gn = n0 + nt * 16 + lm;
    float bv = bias[gn];
#pragma unroll
    for (int rg = 0; rg < 4; rg++) {
      int gm = m0 + w * 16 + q8 * 4 + rg;
      C[(size_t)gm * 512 + gn] = acc[nt][rg] + bv;
    }
  }
}

// ---------------- attention: scores then softmax+PV, per (b,h) -----------
template <int S>
__global__ __launch_bounds__(256)
void attn_scores(const float* __restrict__ Q, const float* __restrict__ K,
                 float* __restrict__ P) {
  __shared__ float Qs[25][64];
  __shared__ float Ks[S][65];
  const int h = blockIdx.x, b = blockIdx.y, t = threadIdx.x;
  for (int idx = t; idx < 25 * 64; idx += 256) {
    int l = idx >> 6, e = idx & 63;
    Qs[l][e] = Q[(b * 25 + l) * 512 + h * 64 + e];
  }
  for (int idx = t; idx < S * 64; idx += 256) {
    int s = idx >> 6, e = idx & 63;
    Ks[s][e] = K[(b * S + s) * 512 + h * 64 + e];
  }
  __syncthreads();
  float* Pb = P + (size_t)(b * 8 + h) * 25 * S;
  for (int idx = t; idx < 25 * S; idx += 256) {
    int l = idx / S, s = idx % S;
    float acc = 0.f;
#pragma unroll
    for (int e = 0; e < 64; e++) acc += Qs[l][e] * Ks[s][e];
    Pb[idx] = acc * 0.125f;
  }
}

template <int S>
__global__ __launch_bounds__(256)
void attn_out(const float* __restrict__ P, const float* __restrict__ V,
              float* __restrict__ O) {
  __shared__ float Ps[25][S];
  __shared__ float Vs[S][64];
  const int h = blockIdx.x, b = blockIdx.y, t = threadIdx.x;
  const float* Pb = P + (size_t)(b * 8 + h) * 25 * S;
  for (int idx = t; idx < 25 * S; idx += 256) Ps[idx / S][idx % S] = Pb[idx];
  for (int idx = t; idx < S * 64; idx += 256) {
    int s = idx >> 6, e = idx & 63;
    Vs[s][e] = V[(b * S + s) * 512 + h * 64 + e];
  }
  __syncthreads();
  if (t < 25) {
    float mx = -1e30f;
    for (int s = 0; s < S; s++) mx = fmaxf(mx, Ps[t][s]);
    float sum = 0.f;
    for (int s = 0; s < S; s++) { float p = __expf(Ps[t][s] - mx); Ps[t][s] = p; sum += p; }
    float r = 1.f / sum;
    for (int s = 0; s < S; s++) Ps[t][s] *= r;
  }
  __syncthreads();
  for (int idx = t; idx < 25 * 64; idx += 256) {
    int l = idx >> 6, e = idx & 63;
    float acc = 0.f;
    for (int s = 0; s < S; s++) acc += Ps[l][s] * Vs[s][e];
    O[(b * 25 + l) * 512 + h * 64 + e] = acc;
  }
}

// ---------------- fused residual-add + LayerNorm (rows of 512) -----------
__global__ __launch_bounds__(128)
void add_ln(const float* __restrict__ a, const float* __restrict__ b,
            const float* __restrict__ gw, const float* __restrict__ bw,
            float* __restrict__ out) {
  const int row = blockIdx.x, t = threadIdx.x;
  float4 va = ((const float4*)(a + (size_t)row * 512))[t];
  float4 vb = ((const float4*)(b + (size_t)row * 512))[t];
  float4 v = make_float4(va.x + vb.x, va.y + vb.y, va.z + vb.z, va.w + vb.w);
  float s = v.x + v.y + v.z + v.w;
  float q = v.x * v.x + v.y * v.y + v.z * v.z + v.w * v.w;
#pragma unroll
  for (int off = 32; off > 0; off >>= 1) {
    s += __shfl_down(s, off);
    q += __shfl_down(q, off);
  }
  __shared__ float red[4];
  if ((t & 63) == 0) { red[(t >> 6) * 2] = s; red[(t >> 6) * 2 + 1] = q; }
  __syncthreads();
  float S_ = red[0] + red[2], Q_ = red[1] + red[3];
  float mean = S_ * (1.f / 512.f);
  float var  = Q_ * (1.f / 512.f) - mean * mean;
  float inv  = rsqrtf(var + EPS_LN);
  float4 g4 = ((const float4*)gw)[t];
  float4 b4 = ((const float4*)bw)[t];
  float4 o;
  o.x = (v.x - mean) * inv * g4.x + b4.x;
  o.y = (v.y - mean) * inv * g4.y + b4.y;
  o.z = (v.z - mean) * inv * g4.z + b4.z;
  o.w = (v.w - mean) * inv * g4.w + b4.w;
  ((float4*)(out + (size_t)row * 512))[t] = o;
}

// ---------------- transposes / LSTM preps --------------------------------
__global__ void transpose_dl(const float* __restrict__ in, float* __restrict__ outp) {
  const int b = blockIdx.x, t = threadIdx.x;
  for (int idx = t; idx < 25 * 512; idx += 256) {
    int l2 = idx / 512, c = idx % 512;
    outp[((size_t)b * 25 + l2) * 512 + c] = in[((size_t)b * 512 + c) * 25 + l2];
  }
}

// X0[b][t=512][32] f16 from x2[b][25][512] (u>=25 pads = 0)
__global__ __launch_bounds__(256)
void prep_x0r(const float* __restrict__ x2, _Float16* __restrict__ X0) {
  __shared__ float tile[25][516];
  const int b = blockIdx.x, t = threadIdx.x;
  for (int idx = t; idx < 25 * 512; idx += 256) {
    int u = idx >> 9, d = idx & 511;
    tile[u][d] = x2[((size_t)b * 25 + u) * 512 + d];
  }
  __syncthreads();
  for (int idx = t; idx < 512 * 32; idx += 256) {
    int d = idx >> 5, u = idx & 31;
    X0[((size_t)b * 512 + d) * 32 + u] = (u < 25) ? (_Float16)tile[u][d] : (_Float16)0.f;
  }
}

// ---------------- pipelined 32-layer LSTM (fdot2, wave-autonomous) -------
// R5 structure: 512 blocks (32 layers x 16 groups of 8 batches), 256 thr,
// wave owns 2 batches -> zero barriers in the step loop. New in R9:
// (a) ring is f16 [l][b][slot64][32] -> staging = 1 x 16B load per thread;
//     producer stores 2B f16 at MALL (relaxed agent, R3-proven protocol);
// (b) ax[8][4] (bias + Wih*x) precomputed densely before the serial loop.
#define NLAY 32
#define NGRP 16
#define BGRP 8
#define CHT  8
#define NCHK 64
#define RSLOTS 64
#define RCHK (RSLOTS / CHT)
#define RLAY ((size_t)128 * RSLOTS * 32)   // halves per layer region

__device__ __forceinline__ int ld_rlx(int* p) {
  return __hip_atomic_load(p, __ATOMIC_RELAXED, __HIP_MEMORY_SCOPE_AGENT);
}
__device__ __forceinline__ void st_rlx(int* p, int v) {
  __hip_atomic_store(p, v, __ATOMIC_RELAXED, __HIP_MEMORY_SCOPE_AGENT);
}
__device__ __forceinline__ unsigned long long ldq_rlx(const unsigned long long* p) {
  return __hip_atomic_load(p, __ATOMIC_RELAXED, __HIP_MEMORY_SCOPE_AGENT);
}
__device__ __forceinline__ void sth_rlx(_Float16* p, _Float16 v) {
  __hip_atomic_store((unsigned short*)p, __builtin_bit_cast(unsigned short, v),
                     __ATOMIC_RELAXED, __HIP_MEMORY_SCOPE_AGENT);
}
__device__ __forceinline__ float tanh_fast(float x) {
  return 1.f - 2.f / (1.f + __expf(2.f * x));
}

__global__ __launch_bounds__(256) __attribute__((amdgpu_waves_per_eu(2, 2)))
void lstm_pipeline(const _Float16* __restrict__ X0, float* __restrict__ yout,
                   _Float16* __restrict__ ring, int* __restrict__ prod,
                   int* __restrict__ cons,
                   const float* __restrict__ Wih, const float* __restrict__ Whh,
                   const float* __restrict__ bih, const float* __restrict__ bhh) {
  const int l = blockIdx.x / NGRP;
  const int g = blockIdx.x % NGRP;
  const int t = threadIdx.x;
  const int u  = t & 31;
  const int bi = t >> 5;
  const bool active = (u < 25);

  __shared__ _Float16 xbuf[CHT][BGRP][32];  // fragment-ready chunk input
  __shared__ _Float16 hbuf[BGRP][32];       // per-batch h (wave-private)

  // ---- weights packed half2: rows {u,25+u,50+u,75+u} (R5-proven) --------
  h2v wih2[4][13], whh2[4][13];
  float bias_r[4];
  float c_reg = 0.f;
  {
    const int uc = active ? u : 24;
#pragma unroll
    for (int j = 0; j < 4; j++) {
      const float* wi = &Wih[((size_t)l * 100 + j * 25 + uc) * 25];
      const float* wh = &Whh[((size_t)l * 100 + j * 25 + uc) * 25];
#pragma unroll
      for (int k = 0; k < 13; k++) {
        float alo = wi[2 * k], ahi = (2 * k + 1 < 25) ? wi[2 * k + 1] : 0.f;
        float blo = wh[2 * k], bhi = (2 * k + 1 < 25) ? wh[2 * k + 1] : 0.f;
        wih2[j][k] = h2v{(_Float16)alo, (_Float16)ahi};
        whh2[j][k] = h2v{(_Float16)blo, (_Float16)bhi};
      }
      bias_r[j] = bih[l * 100 + j * 25 + uc] + bhh[l * 100 + j * 25 + uc];
    }
  }
  for (int idx = t; idx < BGRP * 32; idx += 256) (&hbuf[0][0])[idx] = (_Float16)0.f;
  __syncthreads();

  // producer out pointers (active threads)
  _Float16* ring_out = ring + (size_t)l * RLAY
                       + ((size_t)(g * BGRP + bi) * RSLOTS) * 32 + u;
  float* yout_out = yout + ((size_t)(g * BGRP + bi) * 512) * 25 + u;

  // staging mapping: thread -> (tc, batch, 8-half segment)
  const int s_tc = t >> 5, s_b2 = (t >> 2) & 7, s_seg = t & 3;

  for (int n = 0; n < NCHK; n++) {
    if (t == 0) {
      if (l > 0) {
        int* p = &prod[(l - 1) * NGRP + g];
        while (ld_rlx(p) < n + 1) __builtin_amdgcn_s_sleep(1);
      }
      if (l < NLAY - 1 && n >= RCHK) {
        int* p = &cons[(l + 1) * NGRP + g];
        while (ld_rlx(p) < n - RCHK + 1) __builtin_amdgcn_s_sleep(1);
      }
    }
    __syncthreads();                                   // (A) poll done
    // ---- stage chunk: ONE 16B load per thread ----
    {
      const int tg = n * CHT + s_tc;
      if (l == 0) {
        const uint4* p = (const uint4*)(X0
            + (((size_t)(g * BGRP + s_b2) * 512) + tg) * 32 + s_seg * 8);
        *(uint4*)&xbuf[s_tc][s_b2][s_seg * 8] = *p;
      } else {
        const unsigned long long* p = (const unsigned long long*)(ring
            + (size_t)(l - 1) * RLAY
            + (((size_t)(g * BGRP + s_b2) * RSLOTS) + (tg & (RSLOTS - 1))) * 32
            + s_seg * 8);
        unsigned long long a = ldq_rlx(p);
        unsigned long long b = ldq_rlx(p + 1);
        *(uint4*)&xbuf[s_tc][s_b2][s_seg * 8] =
            make_uint4((unsigned)a, (unsigned)(a >> 32),
                       (unsigned)b, (unsigned)(b >> 32));
      }
    }
    __syncthreads();                                   // (B) staging visible
    if (t == 0 && l > 0) st_rlx(&cons[l * NGRP + g], n + 1);

    // ---- x-part for all 8 steps: dense, latency-free ----
    float ax[CHT][4];
    if (active) {
#pragma unroll
      for (int tc = 0; tc < CHT; tc++) {
        const unsigned int* xr = (const unsigned int*)&xbuf[tc][bi][0];
        uint4 xa = *(const uint4*)(xr);
        uint4 xb = *(const uint4*)(xr + 4);
        uint4 xc = *(const uint4*)(xr + 8);
        unsigned int xd = xr[12];
        h2v xk[13] = {bch2(xa.x), bch2(xa.y), bch2(xa.z), bch2(xa.w),
                      bch2(xb.x), bch2(xb.y), bch2(xb.z), bch2(xb.w),
                      bch2(xc.x), bch2(xc.y), bch2(xc.z), bch2(xc.w),
                      bch2(xd)};
        float a0 = bias_r[0], a1 = bias_r[1], a2 = bias_r[2], a3 = bias_r[3];
#pragma unroll
        for (int k = 0; k < 13; k++) {
          a0 = fdot2(wih2[0][k], xk[k], a0);
          a1 = fdot2(wih2[1][k], xk[k], a1);
          a2 = fdot2(wih2[2][k], xk[k], a2);
          a3 = fdot2(wih2[3][k], xk[k], a3);
        }
        ax[tc][0] = a0; ax[tc][1] = a1; ax[tc][2] = a2; ax[tc][3] = a3;
      }
    }

    // ---- serial h-recurrence: 8 steps, zero barriers ----
#pragma unroll
    for (int tc = 0; tc < CHT; tc++) {
      const int tg = n * CHT + tc;
      if (active) {
        const unsigned int* hr = (const unsigned int*)&hbuf[bi][0];
        uint4 ha = *(const uint4*)(hr);
        uint4 hb = *(const uint4*)(hr + 4);
        uint4 hc = *(const uint4*)(hr + 8);
        unsigned int hd = hr[12];
        h2v hk[13] = {bch2(ha.x), bch2(ha.y), bch2(ha.z), bch2(ha.w),
                      bch2(hb.x), bch2(hb.y), bch2(hb.z), bch2(hb.w),
                      bch2(hc.x), bch2(hc.y), bch2(hc.z), bch2(hc.w),
                      bch2(hd)};
        float a0 = ax[tc][0], a1 = ax[tc][1], a2 = ax[tc][2], a3 = ax[tc][3];
#pragma unroll
        for (int k = 0; k < 13; k++) {
          a0 = fdot2(whh2[0][k], hk[k], a0);
          a1 = fdot2(whh2[1][k], hk[k], a1);
          a2 = fdot2(whh2[2][k], hk[k], a2);
          a3 = fdot2(whh2[3][k], hk[k], a3);
        }
        float si = 1.f / (1.f + __expf(-a0));
        float sf = 1.f / (1.f + __expf(-a1));
        float so = 1.f / (1.f + __expf(-a3));
        c_reg = sf * c_reg + si * tanh_fast(a2);
        float h = so * tanh_fast(c_reg);
        _Float16 h16 = (_Float16)h;
        hbuf[bi][u] = h16;                             // wave-local
        if (l == NLAY - 1)
          yout_out[(size_t)tg * 25] = h;
        else
          sth_rlx(ring_out + (size_t)(tg & (RSLOTS - 1)) * 32, h16);
      }
    }
    asm volatile("s_waitcnt vmcnt(0)" ::: "memory");   // ring stores at MALL
    __syncthreads();                                   // (C) all waves done
    if (t == 0 && l < NLAY - 1) st_rlx(&prod[l * NGRP + g], n + 1);
  }
}

// =====================================================================
extern "C" void kernel_launch(void* const* d_in, const int* in_sizes, int n_in,
                              void* d_out, int out_size, void* d_ws, size_t ws_size,
                              hipStream_t stream) {
  const float* x     = (const float*)d_in[0];
  const float* cross = (const float*)d_in[1];
  const float* Wq_s = (const float*)d_in[2];  const float* bq_s = (const float*)d_in[3];
  const float* Wk_s = (const float*)d_in[4];  const float* bk_s = (const float*)d_in[5];
  const float* Wv_s = (const float*)d_in[6];  const float* bv_s = (const float*)d_in[7];
  const float* Wo_s = (const float*)d_in[8];  const float* bo_s = (const float*)d_in[9];
  const float* Wq_c = (const float*)d_in[10]; const float* bq_c = (const float*)d_in[11];
  const float* Wk_c = (const float*)d_in[12]; const float* bk_c = (const float*)d_in[13];
  const float* Wv_c = (const float*)d_in[14]; const float* bv_c = (const float*)d_in[15];
  const float* Wo_c = (const float*)d_in[16]; const float* bo_c = (const float*)d_in[17];
  const float* g1 = (const float*)d_in[18]; const float* b1 = (const float*)d_in[19];
  const float* g2 = (const float*)d_in[20]; const float* b2 = (const float*)d_in[21];
  const float* g3 = (const float*)d_in[22]; const float* b3 = (const float*)d_in[23];
  const float* Wih = (const float*)d_in[24];
  const float* Whh = (const float*)d_in[25];
  const float* bih = (const float*)d_in[26];
  const float* bhh = (const float*)d_in[27];
  const float* Wc  = (const float*)d_in[28]; const float* bc = (const float*)d_in[29];
  float* out = (float*)d_out;
  float* ws  = (float*)d_ws;

  // ---- workspace (floats); time-multiplexed regions ---------------------
  constexpr size_t A  = 1638400;    // 3200*512
  constexpr size_t C6 = 6291456;    // 12288*512
  float* x1    = ws;
  float* Qc    = ws + A;
  // self phase
  float* Qs    = ws + 2 * A;
  float* Ks    = ws + 3 * A;
  float* Vs    = ws + 4 * A;
  float* attns = ws + 5 * A;
  float* tmp   = ws + 6 * A;
  float* Ps    = ws + 7 * A;
  // cross phase
  float* Kc    = ws + 2 * A;
  float* Vc    = ws + 2 * A + C6;
  float* attnc = ws + 2 * A + 2 * C6;
  float* Pc    = attnc + A;
  float* tmp2  = ws + 6 * A;
  float* x2    = ws + 3 * A;
  // lstm / post
  _Float16* X0b  = (_Float16*)(ws + 4 * A);      // 128*512*32 halves = 1.05M fl
  float*    youtb = ws + 5 * A;                  // [128][512][25] fp32
  _Float16* ringb = (_Float16*)(ws + 6 * A);     // 31*RLAY = 8.13M halves
  float* ytb   = ws + 2 * A;
  float* fy    = ws + 5 * A;                     // after youtb dead
  _Float16* WTall = (_Float16*)(ws + 20000000);
  int* ctr = (int*)(ws + 21179648);

  dim3 blk(256);
  WPtrs wpq;
  wpq.p[0] = Wq_s; wpq.p[1] = Wk_s; wpq.p[2] = Wv_s; wpq.p[3] = Wo_s;
  wpq.p[4] = Wq_c; wpq.p[5] = Wk_c; wpq.p[6] = Wv_c; wpq.p[7] = Wo_c;
  wpq.p[8] = Wc;
  prep_weights<<<dim3(16, 16, 9), blk, 0, stream>>>(wpq, WTall);
  hipMemsetAsync(ctr, 0, 1024 * sizeof(int), stream);
  _Float16* WT[9];
  for (int i = 0; i < 9; i++) WT[i] = WTall + (size_t)i * 262144;

  // ---- self attention ----
  gemm3<<<dim3(24, 50), blk, 0, stream>>>(x, WT[0], WT[1], WT[2],
                                          bq_s, bk_s, bv_s, Qs, Ks, Vs, 3200);
  attn_scores<25><<<dim3(8, 128), blk, 0, stream>>>(Qs, Ks, Ps);
  attn_out<25><<<dim3(8, 128), blk, 0, stream>>>(Ps, Vs, attns);
  gemm3<<<dim3(8, 50), blk, 0, stream>>>(attns, WT[3], WT[3], WT[3],
                                         bo_s, bo_s, bo_s, tmp, tmp, tmp, 3200);
  add_ln<<<3200, 128, 0, stream>>>(x, tmp, g1, b1, x1);
  // ---- cross attention ----
  gemm3<<<dim3(8, 50), blk, 0, stream>>>(x1, WT[4], WT[4], WT[4],
                                         bq_c, bq_c, bq_c, Qc, Qc, Qc, 3200);
  gemm3<<<dim3(16, 192), blk, 0, stream>>>(cross, WT[5], WT[6], WT[6],
                                           bk_c, bv_c, bv_c, Kc, Vc, Vc, 12288);
  attn_scores<96><<<dim3(8, 128), blk, 0, stream>>>(Qc, Kc, Pc);
  attn_out<96><<<dim3(8, 128), blk, 0, stream>>>(Pc, Vc, attnc);
  gemm3<<<dim3(8, 50), blk, 0, stream>>>(attnc, WT[7], WT[7], WT[7],
                                         bo_c, bo_c, bo_c, tmp2, tmp2, tmp2, 3200);
  add_ln<<<3200, 128, 0, stream>>>(x1, tmp2, g2, b2, x2);
  // ---- LSTM over feature axis ----
  prep_x0r<<<128, 256, 0, stream>>>(x2, X0b);
  lstm_pipeline<<<NLAY * NGRP, 256, 0, stream>>>(X0b, youtb, ringb, ctr, ctr + 512,
                                                 Wih, Whh, bih, bhh);
  // ---- pointwise conv over channels + final LN ----
  transpose_dl<<<128, 256, 0, stream>>>(youtb, ytb);
  gemm3<<<dim3(8, 50), blk, 0, stream>>>(ytb, WT[8], WT[8], WT[8],
                                         bc, bc, bc, fy, fy, fy, 3200);
  add_ln<<<3200, 128, 0, stream>>>(x2, fy, g3, b3, out);
}